// Round 5
// baseline (29.367 us; speedup 1.0000x reference)
//
#include <hip/hip_runtime.h>

// Time2Vec: out[b,s, i*64+j] = (j==0) ? (x[b,s,i]*w[i,j]+b[i,j])
//                                     : sin(x[b,s,i]*w[i,j]+b[i,j])
// B=32, S=2048, D=8, E=64  ->  ROWS=65536 rows of 512 f32 outputs.
// Write-BW-bound: 134 MB out, 2 MB in.
// History: R1 plain float4 loop = 26.9us (best). R3 nontemporal = 28.0 (hurt).
// R4 unroll x4 const-stride = 28.4 (hurt). This round: PHASE SEPARATION —
// preload all 16 x-scalars per thread up front, then a pure compute+store
// stream (no reads mixed into the write burst, like fillBuffer).

constexpr int D_IN  = 8;
constexpr int E_PER = 64;
constexpr int CHANS = D_IN * E_PER;      // 512
constexpr int ROWS  = 32 * 2048;         // 65536
constexpr int TOTAL = ROWS * CHANS;      // 33,554,432

typedef float vf4 __attribute__((ext_vector_type(4)));

constexpr int NTHREADS  = 2048 * 256;            // one full-residency grid
constexpr int STRIDE_EL = NTHREADS * 4;          // 2,097,152 elems = 4096 rows
constexpr int X_STRIDE  = (STRIDE_EL / CHANS) * D_IN;  // 32768 x-elems per step
constexpr int NITER     = TOTAL / STRIDE_EL;     // 16 float4s per thread

__global__ __launch_bounds__(256) void time2vec_kernel(
    const float* __restrict__ x,      // [ROWS, 8]
    const float* __restrict__ w,      // [8, 64]
    const float* __restrict__ b,      // [8, 64]
    float* __restrict__ out)          // [ROWS, 512]
{
    const int tid = blockIdx.x * blockDim.x + threadIdx.x;

    // Channel within the 512-wide row is loop-invariant for this thread.
    const int c = (tid * 4) & (CHANS - 1);
    const int i = c >> 6;        // input feature (0..7)
    const int j = c & 63;        // column within the 64-wide embed (mult of 4)

    const vf4 w4 = *reinterpret_cast<const vf4*>(w + i * E_PER + j);
    const vf4 b4 = *reinterpret_cast<const vf4*>(b + i * E_PER + j);
    const bool lin0 = (j == 0);

    // ---- Phase 1: load ALL x values this thread will ever need (16 scalars,
    // static indices -> registers). One burst, one drain.
    const float* xp = x + (tid >> 7) * D_IN + i;   // (tid*4)>>9 rows * 8 + i
    float xv[NITER];
#pragma unroll
    for (int k = 0; k < NITER; ++k)
        xv[k] = xp[k * X_STRIDE];

    // ---- Phase 2: pure compute + store stream (no reads).
    float* op = out + tid * 4;
#pragma unroll
    for (int k = 0; k < NITER; ++k) {
        const float xk = xv[k];
        vf4 r;
        const float a0 = fmaf(xk, w4.x, b4.x);
        r.x = lin0 ? a0 : __sinf(a0);
        r.y = __sinf(fmaf(xk, w4.y, b4.y));
        r.z = __sinf(fmaf(xk, w4.z, b4.z));
        r.w = __sinf(fmaf(xk, w4.w, b4.w));
        *reinterpret_cast<vf4*>(op + k * STRIDE_EL) = r;
    }
}

extern "C" void kernel_launch(void* const* d_in, const int* in_sizes, int n_in,
                              void* d_out, int out_size, void* d_ws, size_t ws_size,
                              hipStream_t stream) {
    const float* x = (const float*)d_in[0];
    const float* w = (const float*)d_in[1];
    const float* b = (const float*)d_in[2];
    float* out = (float*)d_out;

    dim3 grid(2048), block(256);
    time2vec_kernel<<<grid, block, 0, stream>>>(x, w, b, out);
}

// Round 6
// 26.886 us; speedup vs baseline: 1.0923x; 1.0923x over previous
//
#include <hip/hip_runtime.h>

// Time2Vec: out[b,s, i*64+j] = (j==0) ? (x[b,s,i]*w[i,j]+b[i,j])
//                                     : sin(x[b,s,i]*w[i,j]+b[i,j])
// B=32, S=2048, D=8, E=64  ->  ROWS=65536 rows of 512 f32 outputs.
//
// FINAL: this is the Round-1 kernel, the best of 4 structurally distinct
// variants (R1 plain 26.9us | R3 nontemporal 28.0 | R4 unroll-x4 28.4 |
// R5 preload-all 29.4; noise ~±1us). Write-BW-bound: 134 MB out @ ~5.1 TB/s.
// Floor model: fill-kernel steady state 7.2 TB/s + 5.4us launch/ramp
// overhead -> ~24.3us floor for this transfer size; we're within ~10%,
// and the residual is per-wave prologue + sin-pipe tail.

constexpr int D_IN  = 8;
constexpr int E_PER = 64;
constexpr int CHANS = D_IN * E_PER;      // 512
constexpr int ROWS  = 32 * 2048;         // 65536
constexpr int TOTAL = ROWS * CHANS;      // 33,554,432 (fits int32)

__global__ __launch_bounds__(256) void time2vec_kernel(
    const float* __restrict__ x,      // [ROWS, 8]
    const float* __restrict__ w,      // [8, 64]
    const float* __restrict__ b,      // [8, 64]
    float* __restrict__ out)          // [ROWS, 512]
{
    const int tid      = blockIdx.x * blockDim.x + threadIdx.x;
    const int nthreads = gridDim.x * blockDim.x;     // multiple of 128 -> stride % 512 == 0

    // Channel within the 512-wide row is loop-invariant for this thread.
    const int c = (tid * 4) & (CHANS - 1);
    const int i = c >> 6;        // which input feature (0..7)
    const int j = c & 63;        // column within the 64-wide embed (multiple of 4)

    const float4 w4 = *reinterpret_cast<const float4*>(w + i * E_PER + j);
    const float4 b4 = *reinterpret_cast<const float4*>(b + i * E_PER + j);
    const bool lin0 = (j == 0);  // only element 0 of the float4 can be the linear one

    const int stride = nthreads * 4;
    for (int o = tid * 4; o < TOTAL; o += stride) {
        const int row = o >> 9;                    // o / 512
        const float xv = x[row * D_IN + i];

        const float a0 = fmaf(xv, w4.x, b4.x);
        const float a1 = fmaf(xv, w4.y, b4.y);
        const float a2 = fmaf(xv, w4.z, b4.z);
        const float a3 = fmaf(xv, w4.w, b4.w);

        float4 r;
        r.x = lin0 ? a0 : __sinf(a0);
        r.y = __sinf(a1);
        r.z = __sinf(a2);
        r.w = __sinf(a3);

        *reinterpret_cast<float4*>(out + o) = r;
    }
}

extern "C" void kernel_launch(void* const* d_in, const int* in_sizes, int n_in,
                              void* d_out, int out_size, void* d_ws, size_t ws_size,
                              hipStream_t stream) {
    const float* x = (const float*)d_in[0];
    const float* w = (const float*)d_in[1];
    const float* b = (const float*)d_in[2];
    float* out = (float*)d_out;

    // 2048 blocks x 256 threads = 524,288 threads -> full 32-wave/CU occupancy.
    dim3 grid(2048), block(256);
    time2vec_kernel<<<grid, block, 0, stream>>>(x, w, b, out);
}